// Round 1
// baseline (843.109 us; speedup 1.0000x reference)
//
#include <hip/hip_runtime.h>

#define N_NODESC 100000
#define N_EDGESC 1600000
#define HID 128
#define BOND 16
#define BN_EPS 1e-5f

// ---------------- weight transpose: Wt[k][c] = W[c][k] ----------------
__global__ __launch_bounds__(256) void transpose_w(
    const float* __restrict__ W1, const float* __restrict__ W2,
    const float* __restrict__ Wb,
    float* __restrict__ Wt1, float* __restrict__ Wt2, float* __restrict__ Wtb) {
  int idx = blockIdx.x * 256 + threadIdx.x;
  if (idx < 16384) {
    int k = idx >> 7, c = idx & 127;
    Wt1[idx] = W1[c * HID + k];
  } else if (idx < 32768) {
    int j = idx - 16384;
    int k = j >> 7, c = j & 127;
    Wt2[j] = W2[c * HID + k];
  } else if (idx < 34816) {
    int j = idx - 32768;
    int k = j >> 7, c = j & 127;
    Wtb[j] = Wb[c * BOND + k];
  }
}

// ---------------- degree histogram ----------------
__global__ __launch_bounds__(256) void hist_k(const int* __restrict__ dst,
                                              int* __restrict__ deg) {
  int e = blockIdx.x * 256 + threadIdx.x;
  if (e < N_EDGESC) atomicAdd(&deg[dst[e]], 1);
}

// ---------------- scan (3-kernel) ----------------
__global__ __launch_bounds__(1024) void scan_a(const int* __restrict__ deg,
                                               int* __restrict__ incl,  // = row_start+1
                                               int* __restrict__ bsum) {
  __shared__ int s[1024];
  int t = threadIdx.x;
  int i = blockIdx.x * 1024 + t;
  int x = (i < N_NODESC) ? deg[i] : 0;
  s[t] = x;
  __syncthreads();
  for (int off = 1; off < 1024; off <<= 1) {
    int v = (t >= off) ? s[t - off] : 0;
    __syncthreads();
    s[t] += v;
    __syncthreads();
  }
  if (i < N_NODESC) incl[i] = s[t];
  if (t == 1023) bsum[blockIdx.x] = s[1023];
}

__global__ void scan_b(const int* __restrict__ bsum, int* __restrict__ boff, int nb) {
  if (blockIdx.x == 0 && threadIdx.x == 0) {
    int run = 0;
    for (int b = 0; b < nb; ++b) { boff[b] = run; run += bsum[b]; }
  }
}

__global__ __launch_bounds__(256) void scan_c(const int* __restrict__ deg,
                                              int* __restrict__ row_start,
                                              int* __restrict__ cursor,
                                              const int* __restrict__ boff) {
  int i = blockIdx.x * 256 + threadIdx.x;
  if (i < N_NODESC) {
    int v = row_start[i + 1] + boff[i >> 10];
    row_start[i + 1] = v;
    cursor[i] = v - deg[i];
    if (i == 0) row_start[0] = 0;
  }
}

// ---------------- CSR fill ----------------
__global__ __launch_bounds__(256) void fill_k(const int* __restrict__ src,
                                              const int* __restrict__ dst,
                                              int* __restrict__ cursor,
                                              int* __restrict__ ssrc,
                                              int* __restrict__ seid) {
  int e = blockIdx.x * 256 + threadIdx.x;
  if (e < N_EDGESC) {
    int d = dst[e];
    int p = atomicAdd(&cursor[d], 1);
    ssrc[p] = src[e];
    seid[p] = e;
  }
}

// ---------------- node-centric feature mailbox: h1[n] = sum features[src] ----------------
__global__ __launch_bounds__(256) void feat_gather(const float* __restrict__ feat,
                                                   const int* __restrict__ rs,
                                                   const int* __restrict__ ssrc,
                                                   float* __restrict__ h1) {
  int wid = threadIdx.x >> 6;
  int lane = threadIdx.x & 63;
  int node = blockIdx.x * 4 + wid;
  if (node >= N_NODESC) return;
  int start = rs[node], end = rs[node + 1];
  float ax0 = 0.f, ay0 = 0.f, ax1 = 0.f, ay1 = 0.f;
  int i = start;
  for (; i + 2 <= end; i += 2) {
    int s0 = ssrc[i], s1 = ssrc[i + 1];
    float2 v0 = *(const float2*)(feat + s0 * HID + lane * 2);
    float2 v1 = *(const float2*)(feat + s1 * HID + lane * 2);
    ax0 += v0.x; ay0 += v0.y;
    ax1 += v1.x; ay1 += v1.y;
  }
  if (i < end) {
    int s0 = ssrc[i];
    float2 v0 = *(const float2*)(feat + s0 * HID + lane * 2);
    ax0 += v0.x; ay0 += v0.y;
  }
  float2 o; o.x = ax0 + ax1; o.y = ay0 + ay1;
  *(float2*)(h1 + node * HID + lane * 2) = o;
}

// ---------------- node-centric edge-feature mailbox: efsum[n] = sum ef[e] ----------------
__global__ __launch_bounds__(256) void ef_gather(const float* __restrict__ ef,
                                                 const int* __restrict__ rs,
                                                 const int* __restrict__ seid,
                                                 float* __restrict__ efsum) {
  int l = threadIdx.x & 15;
  int node = blockIdx.x * 16 + (threadIdx.x >> 4);
  if (node >= N_NODESC) return;
  int start = rs[node], end = rs[node + 1];
  float a = 0.f;
  for (int i = start; i < end; ++i) {
    int e = seid[i];
    a += ef[e * BOND + l];
  }
  efsum[node * BOND + l] = a;
}

// ---------------- GEMM (f32 VALU) + fused column stats ----------------
// out[i][c] = A[i][:] . Wt[:][c] + bias[c]
//   (+ L1: efsum[i][:] . Wtb[:][c] + deg[i]*bb[c])
//   (+ !L1: F[i][c])
// also accumulates per-column sum and sum-of-squares into ssum/ssq.
template <bool L1>
__global__ __launch_bounds__(256) void gemm_k(
    const float* __restrict__ A, const float* __restrict__ Wt,
    const float* __restrict__ bias,
    const float* __restrict__ Es, const float* __restrict__ Wtb,
    const float* __restrict__ bb, const int* __restrict__ rs,
    const float* __restrict__ F,
    float* __restrict__ outp, float* __restrict__ ssum, float* __restrict__ ssq,
    int nrows) {
  __shared__ float sWt[HID * HID];   // 64KB, [k][c]
  __shared__ float sA[64][132];      // [row][k], padded: b128 reads 2-way max
  __shared__ float sE[64][20];       // [row][j]
  __shared__ float sWtb[BOND * HID]; // [j][c]
  __shared__ float sDeg[64];

  const int tid = threadIdx.x;
  const int tx = tid & 15;   // col groups: cols 4*tx..+3 and 64+4*tx..+3
  const int ty = tid >> 4;   // row group: rows 4*ty..+3
  const int r0 = blockIdx.x * 64;

  for (int idx = tid; idx < HID * HID / 4; idx += 256) {
    float4 v = ((const float4*)Wt)[idx];
    *(float4*)&sWt[idx * 4] = v;
  }
  for (int lin = tid; lin < 64 * 32; lin += 256) {
    int row = lin >> 5;
    int k0 = (lin & 31) << 2;
    int gr = r0 + row;
    float4 v;
    if (gr < nrows) v = *(const float4*)&A[gr * HID + k0];
    else v = make_float4(0.f, 0.f, 0.f, 0.f);
    *(float4*)&sA[row][k0] = v;
  }
  if (L1) {
    for (int idx = tid; idx < BOND * HID / 4; idx += 256) {
      float4 v = ((const float4*)Wtb)[idx];
      *(float4*)&sWtb[idx * 4] = v;
    }
    for (int lin = tid; lin < 64 * 4; lin += 256) {
      int row = lin >> 2;
      int j0 = (lin & 3) << 2;
      int gr = r0 + row;
      float4 v;
      if (gr < nrows) v = *(const float4*)&Es[gr * BOND + j0];
      else v = make_float4(0.f, 0.f, 0.f, 0.f);
      *(float4*)&sE[row][j0] = v;
    }
    if (tid < 64) {
      int gr = r0 + tid;
      sDeg[tid] = (gr < nrows) ? (float)(rs[gr + 1] - rs[gr]) : 0.f;
    }
  }
  __syncthreads();

  float acc[4][8];
#pragma unroll
  for (int r = 0; r < 4; ++r)
#pragma unroll
    for (int c = 0; c < 8; ++c) acc[r][c] = 0.f;

  for (int k0 = 0; k0 < HID; k0 += 4) {
    float4 a[4];
#pragma unroll
    for (int r = 0; r < 4; ++r) a[r] = *(const float4*)&sA[4 * ty + r][k0];
#pragma unroll
    for (int kk = 0; kk < 4; ++kk) {
      float4 w0 = *(const float4*)&sWt[(k0 + kk) * HID + 4 * tx];
      float4 w1 = *(const float4*)&sWt[(k0 + kk) * HID + 64 + 4 * tx];
#pragma unroll
      for (int r = 0; r < 4; ++r) {
        float av = ((const float*)&a[r])[kk];
        acc[r][0] += av * w0.x; acc[r][1] += av * w0.y;
        acc[r][2] += av * w0.z; acc[r][3] += av * w0.w;
        acc[r][4] += av * w1.x; acc[r][5] += av * w1.y;
        acc[r][6] += av * w1.z; acc[r][7] += av * w1.w;
      }
    }
  }
  if (L1) {
    for (int j0 = 0; j0 < BOND; j0 += 4) {
      float4 e[4];
#pragma unroll
      for (int r = 0; r < 4; ++r) e[r] = *(const float4*)&sE[4 * ty + r][j0];
#pragma unroll
      for (int jj = 0; jj < 4; ++jj) {
        float4 w0 = *(const float4*)&sWtb[(j0 + jj) * HID + 4 * tx];
        float4 w1 = *(const float4*)&sWtb[(j0 + jj) * HID + 64 + 4 * tx];
#pragma unroll
        for (int r = 0; r < 4; ++r) {
          float av = ((const float*)&e[r])[jj];
          acc[r][0] += av * w0.x; acc[r][1] += av * w0.y;
          acc[r][2] += av * w0.z; acc[r][3] += av * w0.w;
          acc[r][4] += av * w1.x; acc[r][5] += av * w1.y;
          acc[r][6] += av * w1.z; acc[r][7] += av * w1.w;
        }
      }
    }
  }

  // ---- epilogue: bias (+deg*bb) (+F), store, per-thread column stats ----
  float4 b0 = *(const float4*)&bias[4 * tx];
  float4 b1v = *(const float4*)&bias[64 + 4 * tx];
  float4 bb0 = make_float4(0.f, 0.f, 0.f, 0.f), bb1 = bb0;
  if (L1) {
    bb0 = *(const float4*)&bb[4 * tx];
    bb1 = *(const float4*)&bb[64 + 4 * tx];
  }
  float cs[8], cq[8];
#pragma unroll
  for (int c = 0; c < 8; ++c) { cs[c] = 0.f; cq[c] = 0.f; }

#pragma unroll
  for (int r = 0; r < 4; ++r) {
    int row = r0 + 4 * ty + r;
    bool valid = row < nrows;
    float dg = L1 ? sDeg[4 * ty + r] : 0.f;
    float v[8];
    v[0] = acc[r][0] + b0.x; v[1] = acc[r][1] + b0.y;
    v[2] = acc[r][2] + b0.z; v[3] = acc[r][3] + b0.w;
    v[4] = acc[r][4] + b1v.x; v[5] = acc[r][5] + b1v.y;
    v[6] = acc[r][6] + b1v.z; v[7] = acc[r][7] + b1v.w;
    if (L1) {
      v[0] += dg * bb0.x; v[1] += dg * bb0.y; v[2] += dg * bb0.z; v[3] += dg * bb0.w;
      v[4] += dg * bb1.x; v[5] += dg * bb1.y; v[6] += dg * bb1.z; v[7] += dg * bb1.w;
    }
    if (valid) {
      if (!L1) {
        float4 f0 = *(const float4*)&F[row * HID + 4 * tx];
        float4 f1 = *(const float4*)&F[row * HID + 64 + 4 * tx];
        v[0] += f0.x; v[1] += f0.y; v[2] += f0.z; v[3] += f0.w;
        v[4] += f1.x; v[5] += f1.y; v[6] += f1.z; v[7] += f1.w;
      }
      float4 o0 = make_float4(v[0], v[1], v[2], v[3]);
      float4 o1 = make_float4(v[4], v[5], v[6], v[7]);
      *(float4*)&outp[row * HID + 4 * tx] = o0;
      *(float4*)&outp[row * HID + 64 + 4 * tx] = o1;
#pragma unroll
      for (int c = 0; c < 8; ++c) { cs[c] += v[c]; cq[c] += v[c] * v[c]; }
    }
  }

  // ---- LDS tree reduce of stats across ty, then one atomic set per block ----
  __syncthreads();  // everyone done reading sA
  float* red = &sA[0][0];      // 2048 floats
  float* redq = red + 2048;    // 2048 floats (sA has 8448 total)
#pragma unroll
  for (int q = 0; q < 4; ++q) {
    red[ty * HID + 4 * tx + q] = cs[q];
    red[ty * HID + 64 + 4 * tx + q] = cs[4 + q];
    redq[ty * HID + 4 * tx + q] = cq[q];
    redq[ty * HID + 64 + 4 * tx + q] = cq[4 + q];
  }
  __syncthreads();
  for (int s = 8; s >= 1; s >>= 1) {
    if (ty < s) {
#pragma unroll
      for (int q = 0; q < 4; ++q) {
        red[ty * HID + 4 * tx + q] += red[(ty + s) * HID + 4 * tx + q];
        red[ty * HID + 64 + 4 * tx + q] += red[(ty + s) * HID + 64 + 4 * tx + q];
        redq[ty * HID + 4 * tx + q] += redq[(ty + s) * HID + 4 * tx + q];
        redq[ty * HID + 64 + 4 * tx + q] += redq[(ty + s) * HID + 64 + 4 * tx + q];
      }
    }
    __syncthreads();
  }
  if (ty == 0) {
#pragma unroll
    for (int q = 0; q < 4; ++q) {
      atomicAdd(&ssum[4 * tx + q], red[4 * tx + q]);
      atomicAdd(&ssum[64 + 4 * tx + q], red[64 + 4 * tx + q]);
      atomicAdd(&ssq[4 * tx + q], redq[4 * tx + q]);
      atomicAdd(&ssq[64 + 4 * tx + q], redq[64 + 4 * tx + q]);
    }
  }
}

// ---------------- BN finalize: scale/shift from stats ----------------
__global__ void bnfinal_k(const float* __restrict__ ssum, const float* __restrict__ ssq,
                          const float* __restrict__ gamma, const float* __restrict__ beta,
                          float* __restrict__ scale, float* __restrict__ shift) {
  int c = threadIdx.x;
  if (c < HID) {
    const float invN = 1.f / (float)N_NODESC;
    float m = ssum[c] * invN;
    float var = ssq[c] * invN - m * m;
    float inv = rsqrtf(var + BN_EPS);
    float sc = gamma[c] * inv;
    scale[c] = sc;
    shift[c] = beta[c] - m * sc;
  }
}

// ---------------- fused BN-apply + ReLU ----------------
__global__ __launch_bounds__(256) void bn_relu_k(const float* __restrict__ t,
                                                 const float* __restrict__ scale,
                                                 const float* __restrict__ shift,
                                                 float* __restrict__ o) {
  int idx = blockIdx.x * 256 + threadIdx.x;
  if (idx >= N_NODESC * HID / 4) return;
  float4 v = ((const float4*)t)[idx];
  int c = (idx & 31) << 2;
  v.x = fmaxf(0.f, fmaf(v.x, scale[c + 0], shift[c + 0]));
  v.y = fmaxf(0.f, fmaf(v.y, scale[c + 1], shift[c + 1]));
  v.z = fmaxf(0.f, fmaf(v.z, scale[c + 2], shift[c + 2]));
  v.w = fmaxf(0.f, fmaf(v.w, scale[c + 3], shift[c + 3]));
  ((float4*)o)[idx] = v;
}

extern "C" void kernel_launch(void* const* d_in, const int* in_sizes, int n_in,
                              void* d_out, int out_size, void* d_ws, size_t ws_size,
                              hipStream_t stream) {
  (void)in_sizes; (void)n_in; (void)out_size; (void)ws_size;
  const float* features   = (const float*)d_in[0];
  const float* edge_feats = (const float*)d_in[1];
  const int*   src        = (const int*)d_in[2];
  const int*   dst        = (const int*)d_in[3];
  const float* Wb         = (const float*)d_in[4];
  const float* bb         = (const float*)d_in[5];
  const float* W1         = (const float*)d_in[6];
  const float* b1         = (const float*)d_in[7];
  const float* W2         = (const float*)d_in[8];
  const float* b2         = (const float*)d_in[9];
  const float* gamma1     = (const float*)d_in[10];
  const float* beta1      = (const float*)d_in[11];
  const float* gamma2     = (const float*)d_in[12];
  const float* beta2      = (const float*)d_in[13];
  float* outp = (float*)d_out;

  char* wsb = (char*)d_ws;
  size_t off = 0;
  auto alloc = [&](size_t nbytes) -> void* {
    off = (off + 255) & ~(size_t)255;
    void* p = wsb + off;
    off += nbytes;
    return p;
  };
  int* deg       = (int*)alloc((size_t)N_NODESC * 4);
  int* cursor    = (int*)alloc((size_t)N_NODESC * 4);
  int* row_start = (int*)alloc((size_t)(N_NODESC + 1) * 4);
  int* bsum      = (int*)alloc(128 * 4);
  int* boff      = (int*)alloc(128 * 4);
  int* ssrc      = (int*)alloc((size_t)N_EDGESC * 4);
  int* seid      = (int*)alloc((size_t)N_EDGESC * 4);
  float* h1      = (float*)alloc((size_t)N_NODESC * HID * 4);
  float* efsum   = (float*)alloc((size_t)N_NODESC * BOND * 4);
  float* tbuf    = (float*)alloc((size_t)N_NODESC * HID * 4);
  float* wt1     = (float*)alloc(HID * HID * 4);
  float* wt2     = (float*)alloc(HID * HID * 4);
  float* wtb     = (float*)alloc(BOND * HID * 4);
  float* stats   = (float*)alloc(512 * 4);
  float* scsh    = (float*)alloc(512 * 4);

  hipMemsetAsync(deg, 0, (size_t)N_NODESC * 4, stream);
  hipMemsetAsync(stats, 0, 512 * 4, stream);

  transpose_w<<<136, 256, 0, stream>>>(W1, W2, Wb, wt1, wt2, wtb);
  hist_k<<<6250, 256, 0, stream>>>(dst, deg);
  scan_a<<<98, 1024, 0, stream>>>(deg, row_start + 1, bsum);
  scan_b<<<1, 1, 0, stream>>>(bsum, boff, 98);
  scan_c<<<391, 256, 0, stream>>>(deg, row_start, cursor, boff);
  fill_k<<<6250, 256, 0, stream>>>(src, dst, cursor, ssrc, seid);
  feat_gather<<<25000, 256, 0, stream>>>(features, row_start, ssrc, h1);
  ef_gather<<<6250, 256, 0, stream>>>(edge_feats, row_start, seid, efsum);

  gemm_k<true><<<1563, 256, 0, stream>>>(h1, wt1, b1, efsum, wtb, bb, row_start,
                                         nullptr, tbuf, stats, stats + 128, N_NODESC);
  bnfinal_k<<<1, 128, 0, stream>>>(stats, stats + 128, gamma1, beta1, scsh, scsh + 128);
  bn_relu_k<<<12500, 256, 0, stream>>>(tbuf, scsh, scsh + 128, tbuf);

  gemm_k<false><<<1563, 256, 0, stream>>>(tbuf, wt2, b2, nullptr, nullptr, nullptr,
                                          nullptr, features, h1, stats + 256,
                                          stats + 384, N_NODESC);
  bnfinal_k<<<1, 128, 0, stream>>>(stats + 256, stats + 384, gamma2, beta2,
                                   scsh + 256, scsh + 384);
  bn_relu_k<<<12500, 256, 0, stream>>>(h1, scsh + 256, scsh + 384, outp);
}

// Round 2
// 551.151 us; speedup vs baseline: 1.5297x; 1.5297x over previous
//
#include <hip/hip_runtime.h>

#define NN 100000
#define NE 1600000
#define HID 128
#define KEXT 160            // padded K: 128 feat | 16 edge | deg | 1 | 14 zero
#define ROWB 320            // bytes per ext row (KEXT * 2)
#define BN_EPS 1e-5f

typedef __attribute__((ext_vector_type(8))) short bf16x8;
typedef __attribute__((ext_vector_type(4))) float f32x4;

__device__ inline unsigned short f2bf(float x) {
  union { float f; unsigned u; } v; v.f = x;
  unsigned r = v.u + 0x7FFFu + ((v.u >> 16) & 1u);
  return (unsigned short)(r >> 16);
}

__device__ inline void gload_lds16(const void* g, void* l) {
  __builtin_amdgcn_global_load_lds((const __attribute__((address_space(1))) void*)g,
                                   (__attribute__((address_space(3))) void*)l, 16, 0, 0);
}

// ---------------- build extended bf16 weight matrices ----------------
// W1e[c][k]: k<128 W1[c][k]; 128..143 Wb[c][k-128]; 144 bb[c]; 145 b1[c]; else 0
// W2e[c][k]: k<128 W2[c][k]; 128 b2[c]; else 0
__global__ __launch_bounds__(256) void wext_k(
    const float* __restrict__ W1, const float* __restrict__ Wb,
    const float* __restrict__ bb, const float* __restrict__ b1,
    const float* __restrict__ W2, const float* __restrict__ b2,
    unsigned short* __restrict__ W1e, unsigned short* __restrict__ W2e) {
  int idx = blockIdx.x * 256 + threadIdx.x;
  if (idx >= 128 * KEXT) return;
  int c = idx / KEXT, k = idx - c * KEXT;
  float v1 = 0.f, v2 = 0.f;
  if (k < 128) { v1 = W1[c * HID + k]; v2 = W2[c * HID + k]; }
  else if (k < 144) v1 = Wb[c * 16 + (k - 128)];
  else if (k == 144) v1 = bb[c];
  else if (k == 145) v1 = b1[c];
  if (k == 128) v2 = b2[c];
  W1e[idx] = f2bf(v1);
  W2e[idx] = f2bf(v2);
}

// ---------------- features f32 -> bf16 (packed pairs) ----------------
__global__ __launch_bounds__(256) void featbf16_k(const float* __restrict__ f,
                                                  unsigned* __restrict__ fb) {
  int i = blockIdx.x * 256 + threadIdx.x;
  if (i >= NN * HID / 2) return;
  float2 v = ((const float2*)f)[i];
  fb[i] = (unsigned)f2bf(v.x) | ((unsigned)f2bf(v.y) << 16);
}

// ---------------- degree histogram ----------------
__global__ __launch_bounds__(256) void hist_k(const int* __restrict__ dst,
                                              int* __restrict__ deg) {
  int e = blockIdx.x * 256 + threadIdx.x;
  if (e < NE) atomicAdd(&deg[dst[e]], 1);
}

// ---------------- scan (3-kernel) ----------------
__global__ __launch_bounds__(1024) void scan_a(const int* __restrict__ deg,
                                               int* __restrict__ incl,
                                               int* __restrict__ bsum) {
  __shared__ int s[1024];
  int t = threadIdx.x;
  int i = blockIdx.x * 1024 + t;
  int x = (i < NN) ? deg[i] : 0;
  s[t] = x;
  __syncthreads();
  for (int off = 1; off < 1024; off <<= 1) {
    int v = (t >= off) ? s[t - off] : 0;
    __syncthreads();
    s[t] += v;
    __syncthreads();
  }
  if (i < NN) incl[i] = s[t];
  if (t == 1023) bsum[blockIdx.x] = s[1023];
}

__global__ void scan_b(const int* __restrict__ bsum, int* __restrict__ boff, int nb) {
  if (blockIdx.x == 0 && threadIdx.x == 0) {
    int run = 0;
    for (int b = 0; b < nb; ++b) { boff[b] = run; run += bsum[b]; }
  }
}

__global__ __launch_bounds__(256) void scan_c(const int* __restrict__ deg,
                                              int* __restrict__ row_start,
                                              int* __restrict__ cursor,
                                              const int* __restrict__ boff) {
  int i = blockIdx.x * 256 + threadIdx.x;
  if (i < NN) {
    int v = row_start[i + 1] + boff[i >> 10];
    row_start[i + 1] = v;
    cursor[i] = v - deg[i];
    if (i == 0) row_start[0] = 0;
  }
}

// ---------------- CSR fill ----------------
__global__ __launch_bounds__(256) void fill_k(const int* __restrict__ src,
                                              const int* __restrict__ dst,
                                              int* __restrict__ cursor,
                                              int* __restrict__ ssrc,
                                              int* __restrict__ seid) {
  int e = blockIdx.x * 256 + threadIdx.x;
  if (e < NE) {
    int d = dst[e];
    int p = atomicAdd(&cursor[d], 1);
    ssrc[p] = src[e];
    seid[p] = e;
  }
}

// ---------------- mailbox: A1[n][0..127] = sum_bf16 features[src] ----------------
__global__ __launch_bounds__(256) void feat_gather(const unsigned* __restrict__ fb,
                                                   const int* __restrict__ rs,
                                                   const int* __restrict__ ssrc,
                                                   unsigned short* __restrict__ A1) {
  int wid = threadIdx.x >> 6, lane = threadIdx.x & 63;
  int node = blockIdx.x * 4 + wid;
  if (node >= NN) return;
  int start = rs[node], end = rs[node + 1];
  float ax0 = 0.f, ay0 = 0.f, ax1 = 0.f, ay1 = 0.f;
  int i = start;
  for (; i + 2 <= end; i += 2) {
    int s0 = ssrc[i], s1 = ssrc[i + 1];
    unsigned p0 = fb[s0 * 64 + lane];
    unsigned p1 = fb[s1 * 64 + lane];
    ax0 += __uint_as_float(p0 << 16); ay0 += __uint_as_float(p0 & 0xffff0000u);
    ax1 += __uint_as_float(p1 << 16); ay1 += __uint_as_float(p1 & 0xffff0000u);
  }
  if (i < end) {
    unsigned p0 = fb[ssrc[i] * 64 + lane];
    ax0 += __uint_as_float(p0 << 16); ay0 += __uint_as_float(p0 & 0xffff0000u);
  }
  unsigned o = (unsigned)f2bf(ax0 + ax1) | ((unsigned)f2bf(ay0 + ay1) << 16);
  *(unsigned*)((char*)A1 + (size_t)node * ROWB + lane * 4) = o;
}

// ---------------- mailbox: A1[n][128..159] = [efsum(16) | deg | 1 | 0...] ----------------
__global__ __launch_bounds__(256) void ef_gather(const float* __restrict__ ef,
                                                 const int* __restrict__ rs,
                                                 const int* __restrict__ seid,
                                                 unsigned short* __restrict__ A1) {
  int l = threadIdx.x & 15;
  int node = blockIdx.x * 16 + (threadIdx.x >> 4);
  if (node >= NN) return;
  int start = rs[node], end = rs[node + 1];
  float a = 0.f;
  for (int i = start; i < end; ++i) a += ef[seid[i] * 16 + l];
  char* rowp = (char*)A1 + (size_t)node * ROWB;
  *(unsigned short*)(rowp + 256 + l * 2) = f2bf(a);
  unsigned short tail = (l == 0) ? f2bf((float)(end - start)) : (l == 1) ? (unsigned short)0x3F80 : (unsigned short)0;
  *(unsigned short*)(rowp + 288 + l * 2) = tail;
}

// ---------------- MFMA GEMM: out[i][c] = A[i][:160] . W[c][:160] (+F) ----------------
// A, W bf16 row-major KEXT wide, LDS-staged with XOR-swizzled 16B columns.
// Stats (col sum / sumsq over valid rows) accumulated via atomics.
template <bool RES>
__global__ __launch_bounds__(256) void gemm_mfma(
    const unsigned short* __restrict__ A, const unsigned short* __restrict__ W,
    const float* __restrict__ F, unsigned short* __restrict__ outb,
    float* __restrict__ ssum, float* __restrict__ ssq) {
  __shared__ __align__(16) char sA[64 * ROWB];    // 20 KB
  __shared__ __align__(16) char sW[128 * ROWB];   // 40 KB

  const int tid = threadIdx.x;
  const int wid = tid >> 6, lane = tid & 63;
  const size_t r0 = (size_t)blockIdx.x * 64;

  // ---- stage A tile (64 rows) and full W via global_load_lds, swizzled source ----
#pragma unroll
  for (int q = 0; q < 5; ++q) {
    int s = q * 256 + tid;
    int row = (s * 3277) >> 16;        // s/20
    int c = s - row * 20;
    int csrc = (c < 16) ? (c ^ (row & 7)) : (16 + ((c - 16) ^ (row & 3)));
    gload_lds16((const char*)A + (r0 + row) * ROWB + csrc * 16,
                sA + (size_t)(q * 256 + wid * 64) * 16);
  }
#pragma unroll
  for (int q = 0; q < 10; ++q) {
    int s = q * 256 + tid;
    int row = (s * 3277) >> 16;
    int c = s - row * 20;
    int csrc = (c < 16) ? (c ^ (row & 7)) : (16 + ((c - 16) ^ (row & 3)));
    gload_lds16((const char*)W + (size_t)row * ROWB + csrc * 16,
                sW + (size_t)(q * 256 + wid * 64) * 16);
  }
  __syncthreads();

  // ---- fragments & MFMA ----
  const int l15 = lane & 15;
  const int kgr = lane >> 4;            // 0..3
  const int arow = wid * 16 + l15;

  bf16x8 afrag[5];
#pragma unroll
  for (int ks = 0; ks < 5; ++ks) {
    int creq = ks * 4 + kgr;
    int csw = (creq < 16) ? (creq ^ (arow & 7)) : (16 + ((creq - 16) ^ (arow & 3)));
    afrag[ks] = *(const bf16x8*)(sA + arow * ROWB + csw * 16);
  }

  f32x4 acc[8];
#pragma unroll
  for (int ct = 0; ct < 8; ++ct) acc[ct] = (f32x4){0.f, 0.f, 0.f, 0.f};

#pragma unroll
  for (int ct = 0; ct < 8; ++ct) {
    int brow = ct * 16 + l15;
#pragma unroll
    for (int ks = 0; ks < 5; ++ks) {
      int creq = ks * 4 + kgr;
      int csw = (creq < 16) ? (creq ^ (brow & 7)) : (16 + ((creq - 16) ^ (brow & 3)));
      bf16x8 bfrag = *(const bf16x8*)(sW + brow * ROWB + csw * 16);
      acc[ct] = __builtin_amdgcn_mfma_f32_16x16x32_bf16(afrag[ks], bfrag, acc[ct], 0, 0, 0);
    }
  }

  // ---- epilogue: (+residual), store bf16, per-column stats ----
  const size_t orow0 = r0 + wid * 16 + kgr * 4;
  float cs[8], cq[8];
#pragma unroll
  for (int ct = 0; ct < 8; ++ct) {
    int col = ct * 16 + l15;
    float s_ = 0.f, q_ = 0.f;
#pragma unroll
    for (int r = 0; r < 4; ++r) {
      size_t row = orow0 + r;
      if (row < NN) {
        float v = acc[ct][r];
        if (RES) v += F[row * HID + col];
        outb[row * HID + col] = f2bf(v);
        s_ += v; q_ += v * v;
      }
    }
    cs[ct] = s_; cq[ct] = q_;
  }

  // reduce over kgr (rows within wave), then cross-wave via LDS, then atomics
#pragma unroll
  for (int ct = 0; ct < 8; ++ct) {
    cs[ct] += __shfl_xor(cs[ct], 16); cs[ct] += __shfl_xor(cs[ct], 32);
    cq[ct] += __shfl_xor(cq[ct], 16); cq[ct] += __shfl_xor(cq[ct], 32);
  }
  __syncthreads();                       // done with sA; reuse for reduction
  float* red = (float*)sA;               // [4][2][128]
  if (lane < 16) {
#pragma unroll
    for (int ct = 0; ct < 8; ++ct) {
      red[wid * 256 + ct * 16 + l15] = cs[ct];
      red[wid * 256 + 128 + ct * 16 + l15] = cq[ct];
    }
  }
  __syncthreads();
  if (tid < 128) {
    float s_ = red[tid] + red[256 + tid] + red[512 + tid] + red[768 + tid];
    float q_ = red[128 + tid] + red[384 + tid] + red[640 + tid] + red[896 + tid];
    atomicAdd(&ssum[tid], s_);
    atomicAdd(&ssq[tid], q_);
  }
}

// ---------------- BN finalize: scale/shift from stats ----------------
__global__ void bnfinal_k(const float* __restrict__ ssum, const float* __restrict__ ssq,
                          const float* __restrict__ gamma, const float* __restrict__ beta,
                          float* __restrict__ scale, float* __restrict__ shift) {
  int c = threadIdx.x;
  if (c < HID) {
    const float invN = 1.f / (float)NN;
    float m = ssum[c] * invN;
    float var = ssq[c] * invN - m * m;
    float inv = rsqrtf(var + BN_EPS);
    float sc = gamma[c] * inv;
    scale[c] = sc;
    shift[c] = beta[c] - m * sc;
  }
}

// ---------------- BN+ReLU -> next-layer bf16 A (with bias/zero tail cols) ----------------
__global__ __launch_bounds__(256) void bn_apply_bf16(const unsigned* __restrict__ t,
                                                     const float* __restrict__ scale,
                                                     const float* __restrict__ shift,
                                                     unsigned short* __restrict__ A2) {
  int wid = threadIdx.x >> 6, lane = threadIdx.x & 63;
  size_t row = (size_t)blockIdx.x * 4 + wid;
  if (row >= NN) return;
  unsigned p = t[row * 64 + lane];
  int c = lane * 2;
  float x = fmaxf(0.f, fmaf(__uint_as_float(p << 16), scale[c], shift[c]));
  float y = fmaxf(0.f, fmaf(__uint_as_float(p & 0xffff0000u), scale[c + 1], shift[c + 1]));
  unsigned* orow = (unsigned*)((char*)A2 + row * ROWB);
  orow[lane] = (unsigned)f2bf(x) | ((unsigned)f2bf(y) << 16);
  if (lane < 16) orow[64 + lane] = (lane == 0) ? 0x3F80u : 0u;  // col128=1.0, rest 0
}

// ---------------- final BN+ReLU -> f32 out ----------------
__global__ __launch_bounds__(256) void bn_final_k(const unsigned* __restrict__ t,
                                                  const float* __restrict__ scale,
                                                  const float* __restrict__ shift,
                                                  float* __restrict__ o) {
  int i = blockIdx.x * 256 + threadIdx.x;
  if (i >= NN * 64) return;
  unsigned p = t[i];
  int c = (i & 63) * 2;
  float2 v;
  v.x = fmaxf(0.f, fmaf(__uint_as_float(p << 16), scale[c], shift[c]));
  v.y = fmaxf(0.f, fmaf(__uint_as_float(p & 0xffff0000u), scale[c + 1], shift[c + 1]));
  ((float2*)o)[i] = v;
}

extern "C" void kernel_launch(void* const* d_in, const int* in_sizes, int n_in,
                              void* d_out, int out_size, void* d_ws, size_t ws_size,
                              hipStream_t stream) {
  (void)in_sizes; (void)n_in; (void)out_size; (void)ws_size;
  const float* features   = (const float*)d_in[0];
  const float* edge_feats = (const float*)d_in[1];
  const int*   src        = (const int*)d_in[2];
  const int*   dst        = (const int*)d_in[3];
  const float* Wb         = (const float*)d_in[4];
  const float* bb         = (const float*)d_in[5];
  const float* W1         = (const float*)d_in[6];
  const float* b1         = (const float*)d_in[7];
  const float* W2         = (const float*)d_in[8];
  const float* b2         = (const float*)d_in[9];
  const float* gamma1     = (const float*)d_in[10];
  const float* beta1      = (const float*)d_in[11];
  const float* gamma2     = (const float*)d_in[12];
  const float* beta2      = (const float*)d_in[13];
  float* outp = (float*)d_out;

  char* wsb = (char*)d_ws;
  size_t off = 0;
  auto alloc = [&](size_t nbytes) -> void* {
    off = (off + 255) & ~(size_t)255;
    void* p = wsb + off;
    off += nbytes;
    return p;
  };
  int* deg       = (int*)alloc((size_t)NN * 4);
  int* cursor    = (int*)alloc((size_t)NN * 4);
  int* row_start = (int*)alloc((size_t)(NN + 1) * 4);
  int* bsum      = (int*)alloc(128 * 4);
  int* boff      = (int*)alloc(128 * 4);
  int* ssrc      = (int*)alloc((size_t)NE * 4);
  int* seid      = (int*)alloc((size_t)NE * 4);
  unsigned* featb = (unsigned*)alloc((size_t)NN * 64 * 4);        // 25.6 MB; reused as t-buffer
  unsigned short* A1e = (unsigned short*)alloc((size_t)100032 * ROWB);
  unsigned short* A2e = (unsigned short*)alloc((size_t)100032 * ROWB);
  unsigned short* W1e = (unsigned short*)alloc(128 * KEXT * 2);
  unsigned short* W2e = (unsigned short*)alloc(128 * KEXT * 2);
  float* stats   = (float*)alloc(512 * 4);
  float* scsh    = (float*)alloc(512 * 4);
  unsigned short* tbuf = (unsigned short*)featb;  // alias: featb dead after feat_gather

  hipMemsetAsync(deg, 0, (size_t)NN * 4, stream);
  hipMemsetAsync(stats, 0, 512 * 4, stream);
  hipMemsetAsync((char*)A1e + (size_t)NN * ROWB, 0, 32 * ROWB, stream);
  hipMemsetAsync((char*)A2e + (size_t)NN * ROWB, 0, 32 * ROWB, stream);

  wext_k<<<80, 256, 0, stream>>>(W1, Wb, bb, b1, W2, b2, W1e, W2e);
  featbf16_k<<<25000, 256, 0, stream>>>(features, featb);
  hist_k<<<6250, 256, 0, stream>>>(dst, deg);
  scan_a<<<98, 1024, 0, stream>>>(deg, row_start + 1, bsum);
  scan_b<<<1, 1, 0, stream>>>(bsum, boff, 98);
  scan_c<<<391, 256, 0, stream>>>(deg, row_start, cursor, boff);
  fill_k<<<6250, 256, 0, stream>>>(src, dst, cursor, ssrc, seid);
  feat_gather<<<25000, 256, 0, stream>>>(featb, row_start, ssrc, A1e);
  ef_gather<<<6250, 256, 0, stream>>>(edge_feats, row_start, seid, A1e);

  gemm_mfma<false><<<1563, 256, 0, stream>>>(A1e, W1e, nullptr, tbuf,
                                             stats, stats + 128);
  bnfinal_k<<<1, 128, 0, stream>>>(stats, stats + 128, gamma1, beta1, scsh, scsh + 128);
  bn_apply_bf16<<<25000, 256, 0, stream>>>((const unsigned*)tbuf, scsh, scsh + 128, A2e);

  gemm_mfma<true><<<1563, 256, 0, stream>>>(A2e, W2e, features, tbuf,
                                            stats + 256, stats + 384);
  bnfinal_k<<<1, 128, 0, stream>>>(stats + 256, stats + 384, gamma2, beta2,
                                   scsh + 256, scsh + 384);
  bn_final_k<<<25000, 256, 0, stream>>>((const unsigned*)tbuf, scsh + 256, scsh + 384, outp);
}

// Round 3
// 498.544 us; speedup vs baseline: 1.6911x; 1.1055x over previous
//
#include <hip/hip_runtime.h>

#define NN 100000
#define NE 1600000
#define HID 128
#define KEXT 160            // padded K: 128 feat | 16 edge | deg | 1 | 14 zero
#define ROWB 320            // bytes per ext row (KEXT * 2)
#define BN_EPS 1e-5f

typedef __attribute__((ext_vector_type(8))) short bf16x8;
typedef __attribute__((ext_vector_type(4))) float f32x4;

__device__ inline unsigned short f2bf(float x) {
  union { float f; unsigned u; } v; v.f = x;
  unsigned r = v.u + 0x7FFFu + ((v.u >> 16) & 1u);
  return (unsigned short)(r >> 16);
}

__device__ inline void gload_lds16(const void* g, void* l) {
  __builtin_amdgcn_global_load_lds((const __attribute__((address_space(1))) void*)g,
                                   (__attribute__((address_space(3))) void*)l, 16, 0, 0);
}

// ---------------- build extended bf16 weight matrices ----------------
__global__ __launch_bounds__(256) void wext_k(
    const float* __restrict__ W1, const float* __restrict__ Wb,
    const float* __restrict__ bb, const float* __restrict__ b1,
    const float* __restrict__ W2, const float* __restrict__ b2,
    unsigned short* __restrict__ W1e, unsigned short* __restrict__ W2e) {
  int idx = blockIdx.x * 256 + threadIdx.x;
  if (idx >= 128 * KEXT) return;
  int c = idx / KEXT, k = idx - c * KEXT;
  float v1 = 0.f, v2 = 0.f;
  if (k < 128) { v1 = W1[c * HID + k]; v2 = W2[c * HID + k]; }
  else if (k < 144) v1 = Wb[c * 16 + (k - 128)];
  else if (k == 144) v1 = bb[c];
  else if (k == 145) v1 = b1[c];
  if (k == 128) v2 = b2[c];
  W1e[idx] = f2bf(v1);
  W2e[idx] = f2bf(v2);
}

// ---------------- features f32 -> bf16 (packed pairs) ----------------
__global__ __launch_bounds__(256) void featbf16_k(const float* __restrict__ f,
                                                  unsigned* __restrict__ fb) {
  int i = blockIdx.x * 256 + threadIdx.x;
  if (i >= NN * HID / 2) return;
  float2 v = ((const float2*)f)[i];
  fb[i] = (unsigned)f2bf(v.x) | ((unsigned)f2bf(v.y) << 16);
}

// ---------------- degree histogram ----------------
__global__ __launch_bounds__(256) void hist_k(const int* __restrict__ dst,
                                              int* __restrict__ deg) {
  int e = blockIdx.x * 256 + threadIdx.x;
  if (e < NE) atomicAdd(&deg[dst[e]], 1);
}

// ---------------- scan (3-kernel) ----------------
__global__ __launch_bounds__(1024) void scan_a(const int* __restrict__ deg,
                                               int* __restrict__ incl,
                                               int* __restrict__ bsum) {
  __shared__ int s[1024];
  int t = threadIdx.x;
  int i = blockIdx.x * 1024 + t;
  int x = (i < NN) ? deg[i] : 0;
  s[t] = x;
  __syncthreads();
  for (int off = 1; off < 1024; off <<= 1) {
    int v = (t >= off) ? s[t - off] : 0;
    __syncthreads();
    s[t] += v;
    __syncthreads();
  }
  if (i < NN) incl[i] = s[t];
  if (t == 1023) bsum[blockIdx.x] = s[1023];
}

__global__ void scan_b(const int* __restrict__ bsum, int* __restrict__ boff, int nb) {
  if (blockIdx.x == 0 && threadIdx.x == 0) {
    int run = 0;
    for (int b = 0; b < nb; ++b) { boff[b] = run; run += bsum[b]; }
  }
}

__global__ __launch_bounds__(256) void scan_c(const int* __restrict__ deg,
                                              int* __restrict__ row_start,
                                              int* __restrict__ cursor,
                                              const int* __restrict__ boff) {
  int i = blockIdx.x * 256 + threadIdx.x;
  if (i < NN) {
    int v = row_start[i + 1] + boff[i >> 10];
    row_start[i + 1] = v;
    cursor[i] = v - deg[i];
    if (i == 0) row_start[0] = 0;
  }
}

// ---------------- CSR fill: packed (src,eid) single 8B store ----------------
__global__ __launch_bounds__(256) void fill_k(const int* __restrict__ src,
                                              const int* __restrict__ dst,
                                              int* __restrict__ cursor,
                                              int2* __restrict__ pairs) {
  int e = blockIdx.x * 256 + threadIdx.x;
  if (e < NE) {
    int d = dst[e];
    int p = atomicAdd(&cursor[d], 1);
    pairs[p] = make_int2(src[e], e);
  }
}

// ---------------- mailbox: A1[n][0..127] = sum_bf16 features[src] ----------------
__global__ __launch_bounds__(256) void feat_gather(const unsigned* __restrict__ fb,
                                                   const int* __restrict__ rs,
                                                   const int2* __restrict__ pairs,
                                                   unsigned short* __restrict__ A1) {
  int wid = threadIdx.x >> 6, lane = threadIdx.x & 63;
  int node = blockIdx.x * 4 + wid;
  if (node >= NN) return;
  int start = rs[node], end = rs[node + 1];
  float ax0 = 0.f, ay0 = 0.f, ax1 = 0.f, ay1 = 0.f;
  float ax2 = 0.f, ay2 = 0.f, ax3 = 0.f, ay3 = 0.f;
  int i = start;
  for (; i + 4 <= end; i += 4) {
    int s0 = pairs[i].x, s1 = pairs[i + 1].x, s2 = pairs[i + 2].x, s3 = pairs[i + 3].x;
    unsigned p0 = fb[s0 * 64 + lane];
    unsigned p1 = fb[s1 * 64 + lane];
    unsigned p2 = fb[s2 * 64 + lane];
    unsigned p3 = fb[s3 * 64 + lane];
    ax0 += __uint_as_float(p0 << 16); ay0 += __uint_as_float(p0 & 0xffff0000u);
    ax1 += __uint_as_float(p1 << 16); ay1 += __uint_as_float(p1 & 0xffff0000u);
    ax2 += __uint_as_float(p2 << 16); ay2 += __uint_as_float(p2 & 0xffff0000u);
    ax3 += __uint_as_float(p3 << 16); ay3 += __uint_as_float(p3 & 0xffff0000u);
  }
  for (; i < end; ++i) {
    unsigned p0 = fb[pairs[i].x * 64 + lane];
    ax0 += __uint_as_float(p0 << 16); ay0 += __uint_as_float(p0 & 0xffff0000u);
  }
  float ax = (ax0 + ax1) + (ax2 + ax3);
  float ay = (ay0 + ay1) + (ay2 + ay3);
  unsigned o = (unsigned)f2bf(ax) | ((unsigned)f2bf(ay) << 16);
  *(unsigned*)((char*)A1 + (size_t)node * ROWB + lane * 4) = o;
}

// ---------------- mailbox: A1[n][128..159] = [efsum(16) | deg | 1 | 0...] ----------------
__global__ __launch_bounds__(256) void ef_gather(const float* __restrict__ ef,
                                                 const int* __restrict__ rs,
                                                 const int2* __restrict__ pairs,
                                                 unsigned short* __restrict__ A1) {
  int l = threadIdx.x & 15;
  int node = blockIdx.x * 16 + (threadIdx.x >> 4);
  if (node >= NN) return;
  int start = rs[node], end = rs[node + 1];
  float a0 = 0.f, a1 = 0.f;
  int i = start;
  for (; i + 2 <= end; i += 2) {
    int e0 = pairs[i].y, e1 = pairs[i + 1].y;
    a0 += ef[e0 * 16 + l];
    a1 += ef[e1 * 16 + l];
  }
  if (i < end) a0 += ef[pairs[i].y * 16 + l];
  float a = a0 + a1;
  char* rowp = (char*)A1 + (size_t)node * ROWB;
  *(unsigned short*)(rowp + 256 + l * 2) = f2bf(a);
  unsigned short tail = (l == 0) ? f2bf((float)(end - start)) : (l == 1) ? (unsigned short)0x3F80 : (unsigned short)0;
  *(unsigned short*)(rowp + 288 + l * 2) = tail;
}

// ---------------- MFMA GEMM: out[i][c] = A[i][:160] . W[c][:160] (+F) ----------------
template <bool RES>
__global__ __launch_bounds__(256) void gemm_mfma(
    const unsigned short* __restrict__ A, const unsigned short* __restrict__ W,
    const float* __restrict__ F, unsigned short* __restrict__ outb,
    float* __restrict__ ssum, float* __restrict__ ssq) {
  __shared__ __align__(16) char sA[64 * ROWB];    // 20 KB
  __shared__ __align__(16) char sW[128 * ROWB];   // 40 KB

  const int tid = threadIdx.x;
  const int wid = tid >> 6, lane = tid & 63;
  const size_t r0 = (size_t)blockIdx.x * 64;

#pragma unroll
  for (int q = 0; q < 5; ++q) {
    int s = q * 256 + tid;
    int row = (s * 3277) >> 16;        // s/20
    int c = s - row * 20;
    int csrc = (c < 16) ? (c ^ (row & 7)) : (16 + ((c - 16) ^ (row & 3)));
    gload_lds16((const char*)A + (r0 + row) * ROWB + csrc * 16,
                sA + (size_t)(q * 256 + wid * 64) * 16);
  }
#pragma unroll
  for (int q = 0; q < 10; ++q) {
    int s = q * 256 + tid;
    int row = (s * 3277) >> 16;
    int c = s - row * 20;
    int csrc = (c < 16) ? (c ^ (row & 7)) : (16 + ((c - 16) ^ (row & 3)));
    gload_lds16((const char*)W + (size_t)row * ROWB + csrc * 16,
                sW + (size_t)(q * 256 + wid * 64) * 16);
  }
  __syncthreads();

  const int l15 = lane & 15;
  const int kgr = lane >> 4;            // 0..3
  const int arow = wid * 16 + l15;

  bf16x8 afrag[5];
#pragma unroll
  for (int ks = 0; ks < 5; ++ks) {
    int creq = ks * 4 + kgr;
    int csw = (creq < 16) ? (creq ^ (arow & 7)) : (16 + ((creq - 16) ^ (arow & 3)));
    afrag[ks] = *(const bf16x8*)(sA + arow * ROWB + csw * 16);
  }

  f32x4 acc[8];
#pragma unroll
  for (int ct = 0; ct < 8; ++ct) acc[ct] = (f32x4){0.f, 0.f, 0.f, 0.f};

#pragma unroll
  for (int ct = 0; ct < 8; ++ct) {
    int brow = ct * 16 + l15;
#pragma unroll
    for (int ks = 0; ks < 5; ++ks) {
      int creq = ks * 4 + kgr;
      int csw = (creq < 16) ? (creq ^ (brow & 7)) : (16 + ((creq - 16) ^ (brow & 3)));
      bf16x8 bfrag = *(const bf16x8*)(sW + brow * ROWB + csw * 16);
      acc[ct] = __builtin_amdgcn_mfma_f32_16x16x32_bf16(afrag[ks], bfrag, acc[ct], 0, 0, 0);
    }
  }

  const size_t orow0 = r0 + wid * 16 + kgr * 4;
  float cs[8], cq[8];
#pragma unroll
  for (int ct = 0; ct < 8; ++ct) {
    int col = ct * 16 + l15;
    float s_ = 0.f, q_ = 0.f;
#pragma unroll
    for (int r = 0; r < 4; ++r) {
      size_t row = orow0 + r;
      if (row < NN) {
        float v = acc[ct][r];
        if (RES) v += F[row * HID + col];
        outb[row * HID + col] = f2bf(v);
        s_ += v; q_ += v * v;
      }
    }
    cs[ct] = s_; cq[ct] = q_;
  }

#pragma unroll
  for (int ct = 0; ct < 8; ++ct) {
    cs[ct] += __shfl_xor(cs[ct], 16); cs[ct] += __shfl_xor(cs[ct], 32);
    cq[ct] += __shfl_xor(cq[ct], 16); cq[ct] += __shfl_xor(cq[ct], 32);
  }
  __syncthreads();
  float* red = (float*)sA;
  if (lane < 16) {
#pragma unroll
    for (int ct = 0; ct < 8; ++ct) {
      red[wid * 256 + ct * 16 + l15] = cs[ct];
      red[wid * 256 + 128 + ct * 16 + l15] = cq[ct];
    }
  }
  __syncthreads();
  if (tid < 128) {
    float s_ = red[tid] + red[256 + tid] + red[512 + tid] + red[768 + tid];
    float q_ = red[128 + tid] + red[384 + tid] + red[640 + tid] + red[896 + tid];
    atomicAdd(&ssum[tid], s_);
    atomicAdd(&ssq[tid], q_);
  }
}

// ---------------- BN finalize ----------------
__global__ void bnfinal_k(const float* __restrict__ ssum, const float* __restrict__ ssq,
                          const float* __restrict__ gamma, const float* __restrict__ beta,
                          float* __restrict__ scale, float* __restrict__ shift) {
  int c = threadIdx.x;
  if (c < HID) {
    const float invN = 1.f / (float)NN;
    float m = ssum[c] * invN;
    float var = ssq[c] * invN - m * m;
    float inv = rsqrtf(var + BN_EPS);
    float sc = gamma[c] * inv;
    scale[c] = sc;
    shift[c] = beta[c] - m * sc;
  }
}

// ---------------- BN+ReLU -> next-layer bf16 A ----------------
__global__ __launch_bounds__(256) void bn_apply_bf16(const unsigned* __restrict__ t,
                                                     const float* __restrict__ scale,
                                                     const float* __restrict__ shift,
                                                     unsigned short* __restrict__ A2) {
  int wid = threadIdx.x >> 6, lane = threadIdx.x & 63;
  size_t row = (size_t)blockIdx.x * 4 + wid;
  if (row >= NN) return;
  unsigned p = t[row * 64 + lane];
  int c = lane * 2;
  float x = fmaxf(0.f, fmaf(__uint_as_float(p << 16), scale[c], shift[c]));
  float y = fmaxf(0.f, fmaf(__uint_as_float(p & 0xffff0000u), scale[c + 1], shift[c + 1]));
  unsigned* orow = (unsigned*)((char*)A2 + row * ROWB);
  orow[lane] = (unsigned)f2bf(x) | ((unsigned)f2bf(y) << 16);
  if (lane < 16) orow[64 + lane] = (lane == 0) ? 0x3F80u : 0u;
}

// ---------------- final BN+ReLU -> f32 out ----------------
__global__ __launch_bounds__(256) void bn_final_k(const unsigned* __restrict__ t,
                                                  const float* __restrict__ scale,
                                                  const float* __restrict__ shift,
                                                  float* __restrict__ o) {
  int i = blockIdx.x * 256 + threadIdx.x;
  if (i >= NN * 64) return;
  unsigned p = t[i];
  int c = (i & 63) * 2;
  float2 v;
  v.x = fmaxf(0.f, fmaf(__uint_as_float(p << 16), scale[c], shift[c]));
  v.y = fmaxf(0.f, fmaf(__uint_as_float(p & 0xffff0000u), scale[c + 1], shift[c + 1]));
  ((float2*)o)[i] = v;
}

extern "C" void kernel_launch(void* const* d_in, const int* in_sizes, int n_in,
                              void* d_out, int out_size, void* d_ws, size_t ws_size,
                              hipStream_t stream) {
  (void)in_sizes; (void)n_in; (void)out_size; (void)ws_size;
  const float* features   = (const float*)d_in[0];
  const float* edge_feats = (const float*)d_in[1];
  const int*   src        = (const int*)d_in[2];
  const int*   dst        = (const int*)d_in[3];
  const float* Wb         = (const float*)d_in[4];
  const float* bb         = (const float*)d_in[5];
  const float* W1         = (const float*)d_in[6];
  const float* b1         = (const float*)d_in[7];
  const float* W2         = (const float*)d_in[8];
  const float* b2         = (const float*)d_in[9];
  const float* gamma1     = (const float*)d_in[10];
  const float* beta1      = (const float*)d_in[11];
  const float* gamma2     = (const float*)d_in[12];
  const float* beta2      = (const float*)d_in[13];
  float* outp = (float*)d_out;

  char* wsb = (char*)d_ws;
  size_t off = 0;
  auto alloc = [&](size_t nbytes) -> void* {
    off = (off + 255) & ~(size_t)255;
    void* p = wsb + off;
    off += nbytes;
    return p;
  };
  int* deg       = (int*)alloc((size_t)NN * 4);
  int* cursor    = (int*)alloc((size_t)NN * 4);
  int* row_start = (int*)alloc((size_t)(NN + 1) * 4);
  int* bsum      = (int*)alloc(128 * 4);
  int* boff      = (int*)alloc(128 * 4);
  int2* pairs    = (int2*)alloc((size_t)NE * 8);
  unsigned* featb = (unsigned*)alloc((size_t)NN * 64 * 4);        // reused as t-buffer
  unsigned short* A1e = (unsigned short*)alloc((size_t)100032 * ROWB);
  unsigned short* A2e = (unsigned short*)alloc((size_t)100032 * ROWB);
  unsigned short* W1e = (unsigned short*)alloc(128 * KEXT * 2);
  unsigned short* W2e = (unsigned short*)alloc(128 * KEXT * 2);
  float* stats   = (float*)alloc(512 * 4);
  float* scsh    = (float*)alloc(512 * 4);
  unsigned short* tbuf = (unsigned short*)featb;  // alias: featb dead after feat_gather

  hipMemsetAsync(deg, 0, (size_t)NN * 4, stream);
  hipMemsetAsync(stats, 0, 512 * 4, stream);
  hipMemsetAsync((char*)A1e + (size_t)NN * ROWB, 0, 32 * ROWB, stream);
  hipMemsetAsync((char*)A2e + (size_t)NN * ROWB, 0, 32 * ROWB, stream);

  wext_k<<<80, 256, 0, stream>>>(W1, Wb, bb, b1, W2, b2, W1e, W2e);
  featbf16_k<<<25000, 256, 0, stream>>>(features, featb);
  hist_k<<<6250, 256, 0, stream>>>(dst, deg);
  scan_a<<<98, 1024, 0, stream>>>(deg, row_start + 1, bsum);
  scan_b<<<1, 1, 0, stream>>>(bsum, boff, 98);
  scan_c<<<391, 256, 0, stream>>>(deg, row_start, cursor, boff);
  fill_k<<<6250, 256, 0, stream>>>(src, dst, cursor, pairs);
  feat_gather<<<25000, 256, 0, stream>>>(featb, row_start, pairs, A1e);
  ef_gather<<<6250, 256, 0, stream>>>(edge_feats, row_start, pairs, A1e);

  gemm_mfma<false><<<1563, 256, 0, stream>>>(A1e, W1e, nullptr, tbuf,
                                             stats, stats + 128);
  bnfinal_k<<<1, 128, 0, stream>>>(stats, stats + 128, gamma1, beta1, scsh, scsh + 128);
  bn_apply_bf16<<<25000, 256, 0, stream>>>((const unsigned*)tbuf, scsh, scsh + 128, A2e);

  gemm_mfma<true><<<1563, 256, 0, stream>>>(A2e, W2e, features, tbuf,
                                            stats + 256, stats + 384);
  bnfinal_k<<<1, 128, 0, stream>>>(stats + 256, stats + 384, gamma2, beta2,
                                   scsh + 256, scsh + 384);
  bn_final_k<<<25000, 256, 0, stream>>>((const unsigned*)tbuf, scsh + 256, scsh + 384, outp);
}

// Round 4
// 452.762 us; speedup vs baseline: 1.8621x; 1.1011x over previous
//
#include <hip/hip_runtime.h>

#define NN 100000
#define NE 1600000
#define HID 128
#define KEXT 160            // padded K: 128 feat | 16 edge | deg | 1 | 14 zero
#define ROWB 320            // bytes per ext row (KEXT * 2)
#define BN_EPS 1e-5f

typedef __attribute__((ext_vector_type(8))) short bf16x8;
typedef __attribute__((ext_vector_type(4))) float f32x4;

__device__ inline unsigned short f2bf(float x) {
  union { float f; unsigned u; } v; v.f = x;
  unsigned r = v.u + 0x7FFFu + ((v.u >> 16) & 1u);
  return (unsigned short)(r >> 16);
}
__device__ inline unsigned pk2(float a, float b) {
  return (unsigned)f2bf(a) | ((unsigned)f2bf(b) << 16);
}
__device__ inline float bflo(unsigned p) { return __uint_as_float(p << 16); }
__device__ inline float bfhi(unsigned p) { return __uint_as_float(p & 0xffff0000u); }
__device__ inline float bfu(unsigned short u) { return __uint_as_float((unsigned)u << 16); }

__device__ inline void gload_lds16(const void* g, void* l) {
  __builtin_amdgcn_global_load_lds((const __attribute__((address_space(1))) void*)g,
                                   (__attribute__((address_space(3))) void*)l, 16, 0, 0);
}

// ---------------- build extended bf16 weight matrices ----------------
__global__ __launch_bounds__(256) void wext_k(
    const float* __restrict__ W1, const float* __restrict__ Wb,
    const float* __restrict__ bb, const float* __restrict__ b1,
    const float* __restrict__ W2, const float* __restrict__ b2,
    unsigned short* __restrict__ W1e, unsigned short* __restrict__ W2e) {
  int idx = blockIdx.x * 256 + threadIdx.x;
  if (idx >= 128 * KEXT) return;
  int c = idx / KEXT, k = idx - c * KEXT;
  float v1 = 0.f, v2 = 0.f;
  if (k < 128) { v1 = W1[c * HID + k]; v2 = W2[c * HID + k]; }
  else if (k < 144) v1 = Wb[c * 16 + (k - 128)];
  else if (k == 144) v1 = bb[c];
  else if (k == 145) v1 = b1[c];
  if (k == 128) v2 = b2[c];
  W1e[idx] = f2bf(v1);
  W2e[idx] = f2bf(v2);
}

// ---------------- features f32 -> bf16 (packed pairs) ----------------
__global__ __launch_bounds__(256) void featbf16_k(const float* __restrict__ f,
                                                  unsigned* __restrict__ fb) {
  int i = blockIdx.x * 256 + threadIdx.x;
  if (i >= NN * HID / 2) return;
  float2 v = ((const float2*)f)[i];
  fb[i] = pk2(v.x, v.y);
}

// ---------------- degree histogram, 4-way privatized ----------------
__global__ __launch_bounds__(256) void hist_k(const int* __restrict__ dst,
                                              int* __restrict__ deg4) {
  int e = blockIdx.x * 256 + threadIdx.x;
  if (e < NE) atomicAdd(&deg4[(blockIdx.x & 3) * NN + dst[e]], 1);
}

// ---------------- scan (3-kernel) over summed 4-copy histogram ----------------
__global__ __launch_bounds__(1024) void scan_a(const int* __restrict__ deg4,
                                               int* __restrict__ incl,
                                               int* __restrict__ bsum) {
  __shared__ int s[1024];
  int t = threadIdx.x;
  int i = blockIdx.x * 1024 + t;
  int x = 0;
  if (i < NN) x = deg4[i] + deg4[NN + i] + deg4[2 * NN + i] + deg4[3 * NN + i];
  s[t] = x;
  __syncthreads();
  for (int off = 1; off < 1024; off <<= 1) {
    int v = (t >= off) ? s[t - off] : 0;
    __syncthreads();
    s[t] += v;
    __syncthreads();
  }
  if (i < NN) incl[i] = s[t];
  if (t == 1023) bsum[blockIdx.x] = s[1023];
}

__global__ void scan_b(const int* __restrict__ bsum, int* __restrict__ boff, int nb) {
  if (blockIdx.x == 0 && threadIdx.x == 0) {
    int run = 0;
    for (int b = 0; b < nb; ++b) { boff[b] = run; run += bsum[b]; }
  }
}

// per-copy cursor bases: cur[c][i] = row_start[i] + sum_{c'<c} h[c'][i]
__global__ __launch_bounds__(256) void scan_c(const int* __restrict__ deg4,
                                              int* __restrict__ row_start,
                                              int* __restrict__ cursor4,
                                              const int* __restrict__ boff) {
  int i = blockIdx.x * 256 + threadIdx.x;
  if (i < NN) {
    int h0 = deg4[i], h1 = deg4[NN + i], h2 = deg4[2 * NN + i], h3 = deg4[3 * NN + i];
    int v = row_start[i + 1] + boff[i >> 10];
    row_start[i + 1] = v;
    int st = v - (h0 + h1 + h2 + h3);
    cursor4[i] = st;
    cursor4[NN + i] = st + h0;
    cursor4[2 * NN + i] = st + h0 + h1;
    cursor4[3 * NN + i] = st + h0 + h1 + h2;
    if (i == 0) row_start[0] = 0;
  }
}

// ---------------- CSR fill, 64B full-line records {src, pad, ef bf16[16], pad} ----------------
__global__ __launch_bounds__(256) void fill_rec(const int* __restrict__ src,
                                                const int* __restrict__ dst,
                                                const float* __restrict__ ef,
                                                int* __restrict__ cursor4,
                                                char* __restrict__ recs) {
  int e = blockIdx.x * 256 + threadIdx.x;
  if (e >= NE) return;
  int d = dst[e];
  int p = atomicAdd(&cursor4[(blockIdx.x & 3) * NN + d], 1);
  const float4* efp = (const float4*)(ef + (size_t)e * 16);
  float4 e0 = efp[0], e1 = efp[1], e2 = efp[2], e3 = efp[3];
  float4* r = (float4*)(recs + (size_t)p * 64);
  float4 w;
  w.x = __int_as_float(src[e]); w.y = 0.f;
  w.z = __uint_as_float(pk2(e0.x, e0.y)); w.w = __uint_as_float(pk2(e0.z, e0.w));
  r[0] = w;
  w.x = __uint_as_float(pk2(e1.x, e1.y)); w.y = __uint_as_float(pk2(e1.z, e1.w));
  w.z = __uint_as_float(pk2(e2.x, e2.y)); w.w = __uint_as_float(pk2(e2.z, e2.w));
  r[1] = w;
  w.x = __uint_as_float(pk2(e3.x, e3.y)); w.y = __uint_as_float(pk2(e3.z, e3.w));
  w.z = 0.f; w.w = 0.f;
  r[2] = w;
  r[3] = make_float4(0.f, 0.f, 0.f, 0.f);
}

// ---------------- merged gather: feat mailbox + ef mailbox from records ----------------
__global__ __launch_bounds__(256) void feg_k(const unsigned* __restrict__ fb,
                                             const int* __restrict__ rs,
                                             const char* __restrict__ recs,
                                             unsigned short* __restrict__ A1) {
  int wid = threadIdx.x >> 6, lane = threadIdx.x & 63;
  int node = blockIdx.x * 4 + wid;
  if (node >= NN) return;
  int start = rs[node], end = rs[node + 1];
  int l15 = lane & 15, grp = lane >> 4;
  float ax0 = 0.f, ay0 = 0.f, ax1 = 0.f, ay1 = 0.f;
  float ax2 = 0.f, ay2 = 0.f, ax3 = 0.f, ay3 = 0.f, efa = 0.f;
  int i = start;
  for (; i + 4 <= end; i += 4) {
    int sv = 0;
    if (lane < 4) sv = *(const int*)(recs + (size_t)(i + lane) * 64);
    int s0 = __shfl(sv, 0), s1 = __shfl(sv, 1), s2 = __shfl(sv, 2), s3 = __shfl(sv, 3);
    unsigned p0 = fb[s0 * 64 + lane];
    unsigned p1 = fb[s1 * 64 + lane];
    unsigned p2 = fb[s2 * 64 + lane];
    unsigned p3 = fb[s3 * 64 + lane];
    efa += bfu(*(const unsigned short*)(recs + (size_t)(i + grp) * 64 + 8 + 2 * l15));
    ax0 += bflo(p0); ay0 += bfhi(p0);
    ax1 += bflo(p1); ay1 += bfhi(p1);
    ax2 += bflo(p2); ay2 += bfhi(p2);
    ax3 += bflo(p3); ay3 += bfhi(p3);
  }
  for (; i < end; ++i) {
    int sv = 0;
    if (lane == 0) sv = *(const int*)(recs + (size_t)i * 64);
    int s0 = __shfl(sv, 0);
    unsigned p0 = fb[s0 * 64 + lane];
    ax0 += bflo(p0); ay0 += bfhi(p0);
    if (lane < 16) efa += bfu(*(const unsigned short*)(recs + (size_t)i * 64 + 8 + 2 * l15));
  }
  efa += __shfl_xor(efa, 16);
  efa += __shfl_xor(efa, 32);
  float ax = (ax0 + ax1) + (ax2 + ax3);
  float ay = (ay0 + ay1) + (ay2 + ay3);
  char* rowp = (char*)A1 + (size_t)node * ROWB;
  *(unsigned*)(rowp + lane * 4) = pk2(ax, ay);
  if (lane < 16) {
    *(unsigned short*)(rowp + 256 + 2 * l15) = f2bf(efa);
    unsigned short tail = (l15 == 0) ? f2bf((float)(end - start))
                        : (l15 == 1) ? (unsigned short)0x3F80 : (unsigned short)0;
    *(unsigned short*)(rowp + 288 + 2 * l15) = tail;
  }
}

// ---------------- fallback path (small workspace): pairs CSR ----------------
__global__ __launch_bounds__(256) void fill_pairs(const int* __restrict__ src,
                                                  const int* __restrict__ dst,
                                                  int* __restrict__ cursor4,
                                                  int2* __restrict__ pairs) {
  int e = blockIdx.x * 256 + threadIdx.x;
  if (e < NE) {
    int d = dst[e];
    int p = atomicAdd(&cursor4[(blockIdx.x & 3) * NN + d], 1);
    pairs[p] = make_int2(src[e], e);
  }
}

__global__ __launch_bounds__(256) void feat_gather(const unsigned* __restrict__ fb,
                                                   const int* __restrict__ rs,
                                                   const int2* __restrict__ pairs,
                                                   unsigned short* __restrict__ A1) {
  int wid = threadIdx.x >> 6, lane = threadIdx.x & 63;
  int node = blockIdx.x * 4 + wid;
  if (node >= NN) return;
  int start = rs[node], end = rs[node + 1];
  float ax0 = 0.f, ay0 = 0.f, ax1 = 0.f, ay1 = 0.f;
  float ax2 = 0.f, ay2 = 0.f, ax3 = 0.f, ay3 = 0.f;
  int i = start;
  for (; i + 4 <= end; i += 4) {
    int s0 = pairs[i].x, s1 = pairs[i + 1].x, s2 = pairs[i + 2].x, s3 = pairs[i + 3].x;
    unsigned p0 = fb[s0 * 64 + lane];
    unsigned p1 = fb[s1 * 64 + lane];
    unsigned p2 = fb[s2 * 64 + lane];
    unsigned p3 = fb[s3 * 64 + lane];
    ax0 += bflo(p0); ay0 += bfhi(p0);
    ax1 += bflo(p1); ay1 += bfhi(p1);
    ax2 += bflo(p2); ay2 += bfhi(p2);
    ax3 += bflo(p3); ay3 += bfhi(p3);
  }
  for (; i < end; ++i) {
    unsigned p0 = fb[pairs[i].x * 64 + lane];
    ax0 += bflo(p0); ay0 += bfhi(p0);
  }
  float ax = (ax0 + ax1) + (ax2 + ax3);
  float ay = (ay0 + ay1) + (ay2 + ay3);
  *(unsigned*)((char*)A1 + (size_t)node * ROWB + lane * 4) = pk2(ax, ay);
}

__global__ __launch_bounds__(256) void ef_gather(const float* __restrict__ ef,
                                                 const int* __restrict__ rs,
                                                 const int2* __restrict__ pairs,
                                                 unsigned short* __restrict__ A1) {
  int l = threadIdx.x & 15;
  int node = blockIdx.x * 16 + (threadIdx.x >> 4);
  if (node >= NN) return;
  int start = rs[node], end = rs[node + 1];
  float a0 = 0.f, a1 = 0.f;
  int i = start;
  for (; i + 2 <= end; i += 2) {
    a0 += ef[pairs[i].y * 16 + l];
    a1 += ef[pairs[i + 1].y * 16 + l];
  }
  if (i < end) a0 += ef[pairs[i].y * 16 + l];
  float a = a0 + a1;
  char* rowp = (char*)A1 + (size_t)node * ROWB;
  *(unsigned short*)(rowp + 256 + l * 2) = f2bf(a);
  unsigned short tail = (l == 0) ? f2bf((float)(end - start))
                      : (l == 1) ? (unsigned short)0x3F80 : (unsigned short)0;
  *(unsigned short*)(rowp + 288 + l * 2) = tail;
}

// ---------------- MFMA GEMM: out[i][c] = A[i][:160] . W[c][:160] (+F) ----------------
template <bool RES>
__global__ __launch_bounds__(256) void gemm_mfma(
    const unsigned short* __restrict__ A, const unsigned short* __restrict__ W,
    const float* __restrict__ F, unsigned short* __restrict__ outb,
    float* __restrict__ ssum, float* __restrict__ ssq) {
  __shared__ __align__(16) char sA[64 * ROWB];    // 20 KB
  __shared__ __align__(16) char sW[128 * ROWB];   // 40 KB

  const int tid = threadIdx.x;
  const int wid = tid >> 6, lane = tid & 63;
  const size_t r0 = (size_t)blockIdx.x * 64;

#pragma unroll
  for (int q = 0; q < 5; ++q) {
    int s = q * 256 + tid;
    int row = (s * 3277) >> 16;        // s/20
    int c = s - row * 20;
    int csrc = (c < 16) ? (c ^ (row & 7)) : (16 + ((c - 16) ^ (row & 3)));
    gload_lds16((const char*)A + (r0 + row) * ROWB + csrc * 16,
                sA + (size_t)(q * 256 + wid * 64) * 16);
  }
#pragma unroll
  for (int q = 0; q < 10; ++q) {
    int s = q * 256 + tid;
    int row = (s * 3277) >> 16;
    int c = s - row * 20;
    int csrc = (c < 16) ? (c ^ (row & 7)) : (16 + ((c - 16) ^ (row & 3)));
    gload_lds16((const char*)W + (size_t)row * ROWB + csrc * 16,
                sW + (size_t)(q * 256 + wid * 64) * 16);
  }
  __syncthreads();

  const int l15 = lane & 15;
  const int kgr = lane >> 4;            // 0..3
  const int arow = wid * 16 + l15;

  bf16x8 afrag[5];
#pragma unroll
  for (int ks = 0; ks < 5; ++ks) {
    int creq = ks * 4 + kgr;
    int csw = (creq < 16) ? (creq ^ (arow & 7)) : (16 + ((creq - 16) ^ (arow & 3)));
    afrag[ks] = *(const bf16x8*)(sA + arow * ROWB + csw * 16);
  }

  f32x4 acc[8];
#pragma unroll
  for (int ct = 0; ct < 8; ++ct) acc[ct] = (f32x4){0.f, 0.f, 0.f, 0.f};

#pragma unroll
  for (int ct = 0; ct < 8; ++ct) {
    int brow = ct * 16 + l15;
#pragma unroll
    for (int ks = 0; ks < 5; ++ks) {
      int creq = ks * 4 + kgr;
      int csw = (creq < 16) ? (creq ^ (brow & 7)) : (16 + ((creq - 16) ^ (brow & 3)));
      bf16x8 bfrag = *(const bf16x8*)(sW + brow * ROWB + csw * 16);
      acc[ct] = __builtin_amdgcn_mfma_f32_16x16x32_bf16(afrag[ks], bfrag, acc[ct], 0, 0, 0);
    }
  }

  const size_t orow0 = r0 + wid * 16 + kgr * 4;
  float cs[8], cq[8];
#pragma unroll
  for (int ct = 0; ct < 8; ++ct) {
    int col = ct * 16 + l15;
    float s_ = 0.f, q_ = 0.f;
#pragma unroll
    for (int r = 0; r < 4; ++r) {
      size_t row = orow0 + r;
      if (row < NN) {
        float v = acc[ct][r];
        if (RES) v += F[row * HID + col];
        outb[row * HID + col] = f2bf(v);
        s_ += v; q_ += v * v;
      }
    }
    cs[ct] = s_; cq[ct] = q_;
  }

#pragma unroll
  for (int ct = 0; ct < 8; ++ct) {
    cs[ct] += __shfl_xor(cs[ct], 16); cs[ct] += __shfl_xor(cs[ct], 32);
    cq[ct] += __shfl_xor(cq[ct], 16); cq[ct] += __shfl_xor(cq[ct], 32);
  }
  __syncthreads();
  float* red = (float*)sA;
  if (lane < 16) {
#pragma unroll
    for (int ct = 0; ct < 8; ++ct) {
      red[wid * 256 + ct * 16 + l15] = cs[ct];
      red[wid * 256 + 128 + ct * 16 + l15] = cq[ct];
    }
  }
  __syncthreads();
  if (tid < 128) {
    float s_ = red[tid] + red[256 + tid] + red[512 + tid] + red[768 + tid];
    float q_ = red[128 + tid] + red[384 + tid] + red[640 + tid] + red[896 + tid];
    atomicAdd(&ssum[tid], s_);
    atomicAdd(&ssq[tid], q_);
  }
}

// ---------------- BN finalize ----------------
__global__ void bnfinal_k(const float* __restrict__ ssum, const float* __restrict__ ssq,
                          const float* __restrict__ gamma, const float* __restrict__ beta,
                          float* __restrict__ scale, float* __restrict__ shift) {
  int c = threadIdx.x;
  if (c < HID) {
    const float invN = 1.f / (float)NN;
    float m = ssum[c] * invN;
    float var = ssq[c] * invN - m * m;
    float inv = rsqrtf(var + BN_EPS);
    float sc = gamma[c] * inv;
    scale[c] = sc;
    shift[c] = beta[c] - m * sc;
  }
}

// ---------------- BN+ReLU -> next-layer bf16 A ----------------
__global__ __launch_bounds__(256) void bn_apply_bf16(const unsigned* __restrict__ t,
                                                     const float* __restrict__ scale,
                                                     const float* __restrict__ shift,
                                                     unsigned short* __restrict__ A2) {
  int wid = threadIdx.x >> 6, lane = threadIdx.x & 63;
  size_t row = (size_t)blockIdx.x * 4 + wid;
  if (row >= NN) return;
  unsigned p = t[row * 64 + lane];
  int c = lane * 2;
  float x = fmaxf(0.f, fmaf(bflo(p), scale[c], shift[c]));
  float y = fmaxf(0.f, fmaf(bfhi(p), scale[c + 1], shift[c + 1]));
  unsigned* orow = (unsigned*)((char*)A2 + row * ROWB);
  orow[lane] = pk2(x, y);
  if (lane < 16) orow[64 + lane] = (lane == 0) ? 0x3F80u : 0u;
}

// ---------------- final BN+ReLU -> f32 out ----------------
__global__ __launch_bounds__(256) void bn_final_k(const unsigned* __restrict__ t,
                                                  const float* __restrict__ scale,
                                                  const float* __restrict__ shift,
                                                  float* __restrict__ o) {
  int i = blockIdx.x * 256 + threadIdx.x;
  if (i >= NN * 64) return;
  unsigned p = t[i];
  int c = (i & 63) * 2;
  float2 v;
  v.x = fmaxf(0.f, fmaf(bflo(p), scale[c], shift[c]));
  v.y = fmaxf(0.f, fmaf(bfhi(p), scale[c + 1], shift[c + 1]));
  ((float2*)o)[i] = v;
}

extern "C" void kernel_launch(void* const* d_in, const int* in_sizes, int n_in,
                              void* d_out, int out_size, void* d_ws, size_t ws_size,
                              hipStream_t stream) {
  (void)in_sizes; (void)n_in; (void)out_size;
  const float* features   = (const float*)d_in[0];
  const float* edge_feats = (const float*)d_in[1];
  const int*   src        = (const int*)d_in[2];
  const int*   dst        = (const int*)d_in[3];
  const float* Wb         = (const float*)d_in[4];
  const float* bb         = (const float*)d_in[5];
  const float* W1         = (const float*)d_in[6];
  const float* b1         = (const float*)d_in[7];
  const float* W2         = (const float*)d_in[8];
  const float* b2         = (const float*)d_in[9];
  const float* gamma1     = (const float*)d_in[10];
  const float* beta1      = (const float*)d_in[11];
  const float* gamma2     = (const float*)d_in[12];
  const float* beta2      = (const float*)d_in[13];
  float* outp = (float*)d_out;

  char* wsb = (char*)d_ws;
  size_t off = 0;
  auto alloc = [&](size_t nbytes) -> void* {
    off = (off + 255) & ~(size_t)255;
    void* p = wsb + off;
    off += nbytes;
    return p;
  };
  int* deg4      = (int*)alloc((size_t)4 * NN * 4);
  int* cursor4   = (int*)alloc((size_t)4 * NN * 4);
  int* row_start = (int*)alloc((size_t)(NN + 1) * 4);
  int* bsum      = (int*)alloc(128 * 4);
  int* boff      = (int*)alloc(128 * 4);
  unsigned* featb = (unsigned*)alloc((size_t)NN * 64 * 4);        // reused as t-buffer
  unsigned short* A1e = (unsigned short*)alloc((size_t)100032 * ROWB);
  unsigned short* W1e = (unsigned short*)alloc(128 * KEXT * 2);
  unsigned short* W2e = (unsigned short*)alloc(128 * KEXT * 2);
  float* stats   = (float*)alloc(512 * 4);
  float* scsh    = (float*)alloc(512 * 4);
  unsigned short* tbuf = (unsigned short*)featb;  // alias: featb dead after gather

  // big path: 64B-record CSR (A2e aliases records; disjoint lifetimes)
  size_t recs_need = ((off + 255) & ~(size_t)255) + (size_t)NE * 64;
  bool big = ws_size >= recs_need;
  char* recs = nullptr;
  int2* pairs = nullptr;
  unsigned short* A2e;
  if (big) {
    recs = (char*)alloc((size_t)NE * 64);
    A2e = (unsigned short*)recs;
  } else {
    pairs = (int2*)alloc((size_t)NE * 8);
    A2e = (unsigned short*)alloc((size_t)100032 * ROWB);
  }

  hipMemsetAsync(deg4, 0, (size_t)4 * NN * 4, stream);
  hipMemsetAsync(stats, 0, 512 * 4, stream);
  hipMemsetAsync((char*)A1e + (size_t)NN * ROWB, 0, 32 * ROWB, stream);

  wext_k<<<80, 256, 0, stream>>>(W1, Wb, bb, b1, W2, b2, W1e, W2e);
  featbf16_k<<<25000, 256, 0, stream>>>(features, featb);
  hist_k<<<6250, 256, 0, stream>>>(dst, deg4);
  scan_a<<<98, 1024, 0, stream>>>(deg4, row_start + 1, bsum);
  scan_b<<<1, 1, 0, stream>>>(bsum, boff, 98);
  scan_c<<<391, 256, 0, stream>>>(deg4, row_start, cursor4, boff);

  if (big) {
    fill_rec<<<6250, 256, 0, stream>>>(src, dst, edge_feats, cursor4, recs);
    feg_k<<<25000, 256, 0, stream>>>(featb, row_start, recs, A1e);
  } else {
    fill_pairs<<<6250, 256, 0, stream>>>(src, dst, cursor4, pairs);
    feat_gather<<<25000, 256, 0, stream>>>(featb, row_start, pairs, A1e);
    ef_gather<<<6250, 256, 0, stream>>>(edge_feats, row_start, pairs, A1e);
  }
  // zero A2e tail rows (records dead from here on in big path)
  hipMemsetAsync((char*)A2e + (size_t)NN * ROWB, 0, 32 * ROWB, stream);

  gemm_mfma<false><<<1563, 256, 0, stream>>>(A1e, W1e, nullptr, tbuf,
                                             stats, stats + 128);
  bnfinal_k<<<1, 128, 0, stream>>>(stats, stats + 128, gamma1, beta1, scsh, scsh + 128);
  bn_apply_bf16<<<25000, 256, 0, stream>>>((const unsigned*)tbuf, scsh, scsh + 128, A2e);

  gemm_mfma<true><<<1563, 256, 0, stream>>>(A2e, W2e, features, tbuf,
                                            stats + 256, stats + 384);
  bnfinal_k<<<1, 128, 0, stream>>>(stats + 256, stats + 384, gamma2, beta2,
                                   scsh + 256, scsh + 384);
  bn_final_k<<<25000, 256, 0, stream>>>((const unsigned*)tbuf, scsh + 256, scsh + 384, outp);
}